// Round 1
// baseline (20972.670 us; speedup 1.0000x reference)
//
#include <hip/hip_runtime.h>
#include <hip/hip_bf16.h>
#include <hip/hip_fp16.h>

// NTM/EMM-GRU scan: B=64, T=512, I=512, H=1024, 3H=3072, P=1024 slots, M=64.
// Strategy (round 1): f16 MFMA GEMMs, fp32 master state, 2 kernels per step
// (stage A: gh = h@Whh^T + EMM read path -> xin ; stage B: gi + gates -> h'),
// h history stored as f16, all T outputs as one batched GEMM at the end.

typedef _Float16 half_t;
typedef _Float16 half8 __attribute__((ext_vector_type(8)));
typedef float f32x4 __attribute__((ext_vector_type(4)));

#define NB 64
#define NT 512
#define NI 512
#define NH 1024
#define G3 3072
#define NP 1024
#define NM 64
#define HB (NB * NH)   // 65536 elements per h snapshot

__device__ __forceinline__ float sigm(float v) { return 1.f / (1.f + __expf(-v)); }

// ---------------- prep: f32->f16 weight conversion, mem transpose, h0 zero ----
__global__ __launch_bounds__(256) void prep_kernel(
    const float* __restrict__ Whh, const float* __restrict__ Wih,
    const float* __restrict__ Wout, const float* __restrict__ mem,
    half_t* __restrict__ Whh16, half_t* __restrict__ Wih16,
    half_t* __restrict__ Wout16, float* __restrict__ memT32,
    half_t* __restrict__ hist0, float* __restrict__ h32_0)
{
    size_t stride = (size_t)gridDim.x * blockDim.x;
    size_t t0 = (size_t)blockIdx.x * blockDim.x + threadIdx.x;
    for (size_t i = t0; i < (size_t)G3 * NH; i += stride) Whh16[i] = (half_t)Whh[i];
    for (size_t i = t0; i < (size_t)G3 * NI; i += stride) Wih16[i] = (half_t)Wih[i];
    for (size_t i = t0; i < (size_t)NI * NH; i += stride) Wout16[i] = (half_t)Wout[i];
    for (size_t i = t0; i < (size_t)NP * NM; i += stride) {
        size_t p = i >> 6, m = i & 63;
        memT32[m * (size_t)NP + p] = mem[i];
    }
    for (size_t i = t0; i < (size_t)HB; i += stride) { hist0[i] = (half_t)0.f; h32_0[i] = 0.f; }
}

// ---------------- stage A: gh GEMM (blocks 0..191) + EMM chain (blocks 192..255)
__global__ __launch_bounds__(256) void step_a(
    int t,
    const half_t* __restrict__ hist,     // h_t at hist + t*HB
    const float* __restrict__ h32prev,
    const half_t* __restrict__ Whh16,
    const float* __restrict__ bhh,
    float* __restrict__ gh32,
    const float* __restrict__ x, const float* __restrict__ mem,
    const float* __restrict__ memT32,
    const float* __restrict__ Wk, const float* __restrict__ bk,
    const float* __restrict__ Wri, const float* __restrict__ bri,
    half_t* __restrict__ xin16)
{
    __shared__ float hb[NH];
    __shared__ float wbuf[NP];
    __shared__ float red[256];
    __shared__ float kqs[NM];
    __shared__ float rds[NM];
    __shared__ float mred[4], sred[4];

    int tid = threadIdx.x;
    if (blockIdx.x < 192) {
        // gh = h16 @ Whh16^T + bhh  -> (64 x 3072) f32
        int widx = tid >> 6, lane = tid & 63;
        int idx = blockIdx.x * 4 + widx;     // 0..767 wave tiles
        int mt = idx & 3, ct = idx >> 2;     // mt rows-tile, ct 0..191 col-tile
        int m0 = mt * 16, n0 = ct * 16;
        int row = lane & 15, kg = lane >> 4;
        const half_t* ap = hist + (size_t)t * HB + (size_t)(m0 + row) * NH + kg * 8;
        const half_t* bp = Whh16 + (size_t)(n0 + row) * NH + kg * 8;
        f32x4 acc = {0.f, 0.f, 0.f, 0.f};
#pragma unroll
        for (int kk = 0; kk < 32; ++kk) {
            half8 a = *(const half8*)(ap + kk * 32);
            half8 b = *(const half8*)(bp + kk * 32);
            acc = __builtin_amdgcn_mfma_f32_16x16x32_f16(a, b, acc, 0, 0, 0);
        }
        int n = n0 + row;
        float bb = bhh[n];
#pragma unroll
        for (int r = 0; r < 4; ++r) {
            int b2 = m0 + kg * 4 + r;
            gh32[(size_t)b2 * G3 + n] = acc[r] + bb;
        }
    } else {
        // EMM chain for batch row b (fp32 VALU; tiny FLOPs, deep dependency)
        int b = blockIdx.x - 192;
        for (int j = tid; j < NH; j += 256) hb[j] = h32prev[(size_t)b * NH + j];
        __syncthreads();
        {   // kq[m] = h . Wk[m,:] + bk[m]
            int m = tid >> 2, q = tid & 3;
            const float* wk = Wk + (size_t)m * NH + q * 256;
            const float* hh = hb + q * 256;
            float s = 0.f;
#pragma unroll 8
            for (int j = 0; j < 256; ++j) s += hh[j] * wk[j];
            red[tid] = s;
        }
        __syncthreads();
        if (tid < 64) kqs[tid] = red[tid*4] + red[tid*4+1] + red[tid*4+2] + red[tid*4+3] + bk[tid];
        __syncthreads();
        // scores + softmax over 1024 slots
        float sc[4]; float lmax = -1e30f;
#pragma unroll
        for (int pi = 0; pi < 4; ++pi) {
            int p = tid * 4 + pi;
            const float* mp = mem + (size_t)p * NM;
            float s = 0.f;
#pragma unroll 8
            for (int m2 = 0; m2 < NM; ++m2) s += kqs[m2] * mp[m2];
            sc[pi] = s; lmax = fmaxf(lmax, s);
        }
        for (int o = 32; o; o >>= 1) lmax = fmaxf(lmax, __shfl_xor(lmax, o));
        if ((tid & 63) == 0) mred[tid >> 6] = lmax;
        __syncthreads();
        float gmax = fmaxf(fmaxf(mred[0], mred[1]), fmaxf(mred[2], mred[3]));
        float lsum = 0.f;
#pragma unroll
        for (int pi = 0; pi < 4; ++pi) {
            float e = __expf(sc[pi] - gmax);
            wbuf[tid * 4 + pi] = e; lsum += e;
        }
        for (int o = 32; o; o >>= 1) lsum += __shfl_xor(lsum, o);
        if ((tid & 63) == 0) sred[tid >> 6] = lsum;
        __syncthreads();
        float winv = 1.f / (sred[0] + sred[1] + sred[2] + sred[3]);
        {   // read[m] = (w . memT[m,:]) * winv
            int m = tid >> 2, q = tid & 3;
            const float* mt2 = memT32 + (size_t)m * NP + q * 256;
            const float* wp = wbuf + q * 256;
            float s = 0.f;
#pragma unroll 8
            for (int j = 0; j < 256; ++j) s += wp[j] * mt2[j];
            red[tid] = s;
        }
        __syncthreads();
        if (tid < 64) rds[tid] = (red[tid*4] + red[tid*4+1] + red[tid*4+2] + red[tid*4+3]) * winv;
        __syncthreads();
        // r = relu(read @ Wri^T + bri); xin = x_t + r  (stored f16)
#pragma unroll
        for (int ii = 0; ii < 2; ++ii) {
            int i0 = tid + ii * 256;
            const float* wri = Wri + (size_t)i0 * NM;
            float s = bri[i0];
#pragma unroll 8
            for (int m2 = 0; m2 < NM; ++m2) s += rds[m2] * wri[m2];
            s = fmaxf(s, 0.f);
            xin16[(size_t)b * NI + i0] =
                (half_t)(x[((size_t)b * NT + t) * NI + i0] + s);
        }
    }
}

// ---------------- stage B: gi GEMM (3 gate tiles) + GRU gates -> h_{t+1} ----
__global__ __launch_bounds__(256) void step_b(
    int t,
    const half_t* __restrict__ xin16,
    const half_t* __restrict__ Wih16,
    const float* __restrict__ bih,
    const float* __restrict__ gh32,
    const float* __restrict__ h32prev,
    float* __restrict__ h32next,
    half_t* __restrict__ hist)
{
    int tid = threadIdx.x;
    int widx = tid >> 6, lane = tid & 63;
    int idx = blockIdx.x * 4 + widx;   // 0..255
    int mt = idx & 3, ct = idx >> 2;   // ct 0..63 over H columns
    int m0 = mt * 16, c = ct * 16;
    int row = lane & 15, kg = lane >> 4;
    const half_t* ap  = xin16 + (size_t)(m0 + row) * NI + kg * 8;
    const half_t* bpR = Wih16 + (size_t)(c + row) * NI + kg * 8;
    const half_t* bpZ = Wih16 + (size_t)(NH + c + row) * NI + kg * 8;
    const half_t* bpN = Wih16 + (size_t)(2 * NH + c + row) * NI + kg * 8;
    f32x4 aR = {0.f,0.f,0.f,0.f}, aZ = {0.f,0.f,0.f,0.f}, aN = {0.f,0.f,0.f,0.f};
#pragma unroll
    for (int kk = 0; kk < 16; ++kk) {
        half8 a = *(const half8*)(ap + kk * 32);
        aR = __builtin_amdgcn_mfma_f32_16x16x32_f16(a, *(const half8*)(bpR + kk * 32), aR, 0, 0, 0);
        aZ = __builtin_amdgcn_mfma_f32_16x16x32_f16(a, *(const half8*)(bpZ + kk * 32), aZ, 0, 0, 0);
        aN = __builtin_amdgcn_mfma_f32_16x16x32_f16(a, *(const half8*)(bpN + kk * 32), aN, 0, 0, 0);
    }
    int n = c + row;
    float biR = bih[n], biZ = bih[NH + n], biN = bih[2 * NH + n];
#pragma unroll
    for (int r = 0; r < 4; ++r) {
        int b = m0 + kg * 4 + r;
        float ghr = gh32[(size_t)b * G3 + n];
        float ghz = gh32[(size_t)b * G3 + NH + n];
        float ghn = gh32[(size_t)b * G3 + 2 * NH + n];
        float rg = sigm(aR[r] + biR + ghr);
        float zg = sigm(aZ[r] + biZ + ghz);
        float ng = tanhf(aN[r] + biN + rg * ghn);
        float hp = h32prev[(size_t)b * NH + n];
        float hn = (1.f - zg) * ng + zg * hp;
        h32next[(size_t)b * NH + n] = hn;
        hist[(size_t)(t + 1) * HB + (size_t)b * NH + n] = (half_t)hn;
    }
}

// ---------------- final: out[b,t,:] = sigmoid(h_{t+1} @ Wout^T + bout) -------
__global__ __launch_bounds__(256) void out_kernel(
    const half_t* __restrict__ hist,    // rows (t*64+b); h_1 starts at +HB
    const half_t* __restrict__ Wout16,
    const float* __restrict__ bout,
    float* __restrict__ out)
{
    int tid = threadIdx.x;
    int widx = tid >> 6, lane = tid & 63;
    int m0 = blockIdx.x * 64 + widx * 16;   // rows over 32768 = (T,B)
    int row = lane & 15, kg = lane >> 4;
    const half_t* ap = hist + HB + (size_t)(m0 + row) * NH + kg * 8;
    for (int ct = 0; ct < 32; ++ct) {
        int n0 = ct * 16;
        const half_t* bp = Wout16 + (size_t)(n0 + row) * NH + kg * 8;
        f32x4 acc = {0.f, 0.f, 0.f, 0.f};
#pragma unroll
        for (int kk = 0; kk < 32; ++kk) {
            acc = __builtin_amdgcn_mfma_f32_16x16x32_f16(
                *(const half8*)(ap + kk * 32), *(const half8*)(bp + kk * 32), acc, 0, 0, 0);
        }
        int n = n0 + row;
        float bo = bout[n];
#pragma unroll
        for (int r = 0; r < 4; ++r) {
            int m = m0 + kg * 4 + r;        // 0..32767
            int b2 = m & 63, tt = m >> 6;   // b, time
            out[((size_t)b2 * NT + tt) * NI + n] = sigm(acc[r] + bo);
        }
    }
}

extern "C" void kernel_launch(void* const* d_in, const int* in_sizes, int n_in,
                              void* d_out, int out_size, void* d_ws, size_t ws_size,
                              hipStream_t stream) {
    const float* x    = (const float*)d_in[0];
    const float* mem  = (const float*)d_in[1];
    const float* Wk   = (const float*)d_in[2];
    const float* bk   = (const float*)d_in[3];
    const float* Wri  = (const float*)d_in[4];
    const float* bri  = (const float*)d_in[5];
    const float* Wih  = (const float*)d_in[6];
    const float* Whh  = (const float*)d_in[7];
    const float* bih  = (const float*)d_in[8];
    const float* bhh  = (const float*)d_in[9];
    const float* Wout = (const float*)d_in[10];
    const float* bout = (const float*)d_in[11];
    float* out = (float*)d_out;

    size_t off = 0;
    char* wsb = (char*)d_ws;
    auto carve = [&](size_t bytes) -> char* {
        char* p = wsb + off;
        off += (bytes + 255) & ~(size_t)255;
        return p;
    };
    half_t* Whh16  = (half_t*)carve((size_t)G3 * NH * 2);
    half_t* Wih16  = (half_t*)carve((size_t)G3 * NI * 2);
    half_t* Wout16 = (half_t*)carve((size_t)NI * NH * 2);
    float*  memT32 = (float*)carve((size_t)NM * NP * 4);
    half_t* hist   = (half_t*)carve((size_t)(NT + 1) * HB * 2);  // 64 MB
    float*  h32    = (float*)carve((size_t)2 * HB * 4);
    float*  gh32   = (float*)carve((size_t)NB * G3 * 4);
    half_t* xin16  = (half_t*)carve((size_t)NB * NI * 2);
    (void)ws_size; (void)in_sizes; (void)n_in; (void)out_size;

    prep_kernel<<<dim3(1024), dim3(256), 0, stream>>>(
        Whh, Wih, Wout, mem, Whh16, Wih16, Wout16, memT32, hist, h32);

    for (int t = 0; t < NT; ++t) {
        float* hprev = h32 + (size_t)(t & 1) * HB;
        float* hnext = h32 + (size_t)((t + 1) & 1) * HB;
        step_a<<<dim3(256), dim3(256), 0, stream>>>(
            t, hist, hprev, Whh16, bhh, gh32,
            x, mem, memT32, Wk, bk, Wri, bri, xin16);
        step_b<<<dim3(64), dim3(256), 0, stream>>>(
            t, xin16, Wih16, bih, gh32, hprev, hnext, hist);
    }
    out_kernel<<<dim3(512), dim3(256), 0, stream>>>(hist, Wout16, bout, out);
}